// Round 14
// baseline (302.154 us; speedup 1.0000x reference)
//
#include <hip/hip_runtime.h>
#include <math.h>

#define NLEV 8
#define D_DIM 1024

struct TB  { float  t[8]; };   // fp32 z-space thresholds (fast path)
struct TBD { double t[8]; };   // fp64 z-space thresholds (repair path)

typedef __attribute__((ext_vector_type(8))) short bf16x8;  // 8 bf16 (4 VGPRs)
typedef __attribute__((ext_vector_type(4))) float f32x4;   // 4 fp32 acc

// RNE float->bf16 (bits in low 16)
__device__ __forceinline__ unsigned bf16_rne_bits(float f) {
    const unsigned u = __float_as_uint(f);
    return (u + 0x7FFFu + ((u >> 16) & 1u)) >> 16;
}
__device__ __forceinline__ float bf16_bits_to_f(unsigned h) {
    return __uint_as_float(h << 16);
}

// ---- DPP rotate-reduce within 16-lane rows (prologue C1/C0 only) ----
template<int CTRL>
__device__ __forceinline__ float ror_add(float v) {
    int r = __builtin_amdgcn_update_dpp(0, __float_as_int(v), CTRL, 0xF, 0xF, true);
    return v + __int_as_float(r);
}
__device__ __forceinline__ float red16(float v) {
    v = ror_add<0x121>(v); v = ror_add<0x122>(v);
    v = ror_add<0x124>(v); v = ror_add<0x128>(v);
    return v;
}
__device__ __forceinline__ float wave_allreduce(float v) {
    v = red16(v);
    v += __shfl_xor(v, 16, 64);
    v += __shfl_xor(v, 32, 64);
    return v;
}

// ---- fp64 repair (field-verified math since R7; x reloaded, L2/L3-hot) ----
__device__ __forceinline__ void repair_row_reload(
        int row, const float* __restrict__ xg,
        const float* __restrict__ gg, const float* __restrict__ bg,
        const float* __restrict__ Wg, float* __restrict__ outg,
        const TBD& tbd, int lane)
{
    const float4* xb4 = (const float4*)(xg + (size_t)row * D_DIM);
    const float4 x0 = xb4[lane];
    const float4 x1 = xb4[64 + lane];
    const float4 x2 = xb4[128 + lane];
    const float4 x3 = xb4[192 + lane];

    double ds = 0.0, dsq = 0.0;
    #pragma unroll
    for (int j = 0; j < 4; ++j) {
        const float4 a = (j == 0) ? x0 : (j == 1) ? x1 : (j == 2) ? x2 : x3;
        const double v0 = (double)a.x, v1 = (double)a.y;
        const double v2 = (double)a.z, v3 = (double)a.w;
        ds += ((v0 + v1) + (v2 + v3));
        dsq = fma(v0, v0, dsq); dsq = fma(v1, v1, dsq);
        dsq = fma(v2, v2, dsq); dsq = fma(v3, v3, dsq);
    }
    #pragma unroll
    for (int off = 32; off >= 1; off >>= 1) {
        ds  += __shfl_xor(ds, off, 64);
        dsq += __shfl_xor(dsq, off, 64);
    }
    const double mean = ds * (1.0 / 1024.0);
    const double var  = dsq * (1.0 / 1024.0) - mean * mean;
    const double rstd = 1.0 / sqrt(var + 1e-5);

    double dacc[NLEV];
    #pragma unroll
    for (int n = 0; n < NLEV; ++n) dacc[n] = 0.0;
    #pragma unroll
    for (int j = 0; j < 4; ++j) {
        const int col = j * 256 + lane * 4;
        const float4 a = (j == 0) ? x0 : (j == 1) ? x1 : (j == 2) ? x2 : x3;
        const float4 g4 = *(const float4*)(gg + col);
        const float4 b4 = *(const float4*)(bg + col);
        const double y0 = fma(((double)a.x - mean) * rstd, (double)g4.x, (double)b4.x);
        const double y1 = fma(((double)a.y - mean) * rstd, (double)g4.y, (double)b4.y);
        const double y2 = fma(((double)a.z - mean) * rstd, (double)g4.z, (double)b4.z);
        const double y3 = fma(((double)a.w - mean) * rstd, (double)g4.w, (double)b4.w);
        #pragma unroll
        for (int n = 0; n < NLEV; ++n) {
            const float4 w4 = *(const float4*)(Wg + n * D_DIM + col);
            dacc[n] = fma(y0, (double)w4.x, dacc[n]);
            dacc[n] = fma(y1, (double)w4.y, dacc[n]);
            dacc[n] = fma(y2, (double)w4.z, dacc[n]);
            dacc[n] = fma(y3, (double)w4.w, dacc[n]);
        }
    }
    #pragma unroll
    for (int off = 32; off >= 1; off >>= 1) {
        #pragma unroll
        for (int n = 0; n < NLEV; ++n) dacc[n] += __shfl_xor(dacc[n], off, 64);
    }
    if (lane < NLEV) {
        double a0d = (lane & 4) ? dacc[4] : dacc[0];
        double a1d = (lane & 4) ? dacc[5] : dacc[1];
        double a2d = (lane & 4) ? dacc[6] : dacc[2];
        double a3d = (lane & 4) ? dacc[7] : dacc[3];
        double b0d = (lane & 2) ? a2d : a0d;
        double b1d = (lane & 2) ? a3d : a1d;
        const double z = (lane & 1) ? b1d : b0d;
        int c = 0;
        #pragma unroll
        for (int k = 0; k < 8; ++k) c += (z > tbd.t[k]) ? 1 : 0;
        outg[(size_t)row * NLEV + lane] = (float)(c - 4);
    }
}

// ------------- MFMA + split-K: 2 waves per 16-row tile, 4 waves/SIMD ----------
// R22 = R21 resubmit (R21 failed on container acquisition — infra, like R3:
// both barriers unconditionally reached, wave-uniform repair, no workspace,
// no graph-capture violations; launch_bounds(256,4) -> 128-VGPR cap under
// BOTH observed semantics).
// Design: R12 proved the MFMA core correct (absmax 0, WRITE 1.03 MB clean)
// but VGPR=196 -> 2 waves/SIMD -> 97 us. Clean occupancy A/B: 2 waves/SIMD =
// 97 us, 4 = 78 us -> occupancy moves this kernel family. Fixes:
//  * split-K: waves h=0/1 each do half of K (16 MFMA steps, 512 cols) of the
//    same 16-row tile -> per-wave serial chain halves; partials merged in LDS.
//  * block 256 thr = 2 tiles x 2 halves = 32 rows; grid 1024 = 4 blocks/CU =
//    16 waves/CU = 4 waves/SIMD.
//  * all R12-verified layouts/numerics (A/B/C maps, RNE Dekker split) as-is.
// GATES: VGPR<=128, WRITE~1.05 MB. Success: fused -> 35-55 us. Clean null
// (>=70 us at 4 waves/SIMD): wall is structure-independent -> declare roofline.
__global__ __launch_bounds__(256, 4) void fsq_mfma(
        const float* __restrict__ xg,
        const float* __restrict__ gg,
        const float* __restrict__ bg,
        const float* __restrict__ Wg,
        float* __restrict__ outg,
        int nrows, TB tb, TBD tbd)
{
    __shared__ __align__(16) short Bf[32 * 64 * 8];   // 32 KB B-fragments (full K)
    __shared__ float redc1[4][NLEV];
    __shared__ float redc0[4][NLEV];
    __shared__ float Sbuf[2][2][16][NLEV];            // [tile][half][row][n] 2 KB
    __shared__ float msbuf[2][2][16][2];              // [tile][half][row][s,sq] 512 B

    const int tid  = (int)threadIdx.x;
    const int lane = tid & 63;
    const int wv   = tid >> 6;            // 0..3
    const int t    = wv >> 1;             // tile 0/1
    const int h    = wv & 1;              // K-half 0/1

    // ---- C1 = sum(g*W), C0 = sum(b*W) block reduction ----
    {
        const int col = tid * 4;          // 256 threads x 4 = 1024
        const float4 g4 = *(const float4*)(gg + col);
        const float4 b4 = *(const float4*)(bg + col);
        float pc1[NLEV], pc0[NLEV];
        #pragma unroll
        for (int n = 0; n < NLEV; ++n) {
            const float4 w4 = *(const float4*)(Wg + n * D_DIM + col);
            pc1[n] = (g4.x * w4.x + g4.y * w4.y) + (g4.z * w4.z + g4.w * w4.w);
            pc0[n] = (b4.x * w4.x + b4.y * w4.y) + (b4.z * w4.z + b4.w * w4.w);
        }
        #pragma unroll
        for (int n = 0; n < NLEV; ++n) {
            pc1[n] = wave_allreduce(pc1[n]);
            pc0[n] = wave_allreduce(pc0[n]);
        }
        if (lane == 0) {
            #pragma unroll
            for (int n = 0; n < NLEV; ++n) { redc1[wv][n] = pc1[n]; redc0[wv][n] = pc0[n]; }
        }
    }

    // ---- build B-fragments in LDS (R12-verified layout) ----
    #pragma unroll 1
    for (int i = 0; i < 8; ++i) {
        const int slot = tid + i * 256;       // 0..2047
        const int ks   = slot >> 6;
        const int ln   = slot & 63;
        const int cn   = ln & 15;
        const int n    = cn & 7;
        const int k0   = ks * 32 + (ln >> 4) * 8;
        const float4 ga  = *(const float4*)(gg + k0);
        const float4 gb2 = *(const float4*)(gg + k0 + 4);
        const float4 wa  = *(const float4*)(Wg + n * D_DIM + k0);
        const float4 wb  = *(const float4*)(Wg + n * D_DIM + k0 + 4);
        float v[8] = { ga.x * wa.x,  ga.y * wa.y,  ga.z * wa.z,  ga.w * wa.w,
                       gb2.x * wb.x, gb2.y * wb.y, gb2.z * wb.z, gb2.w * wb.w };
        bf16x8 frag;
        if (cn < 8) {
            #pragma unroll
            for (int e = 0; e < 8; ++e) frag[e] = (short)bf16_rne_bits(v[e]);
        } else {
            #pragma unroll
            for (int e = 0; e < 8; ++e) {
                const unsigned hb = bf16_rne_bits(v[e]);
                frag[e] = (short)bf16_rne_bits(v[e] - bf16_bits_to_f(hb));
            }
        }
        *(bf16x8*)&Bf[slot * 8] = frag;
    }
    __syncthreads();

    const int nsel = lane & 7;
    const float C1sel = redc1[0][nsel] + redc1[1][nsel] + redc1[2][nsel] + redc1[3][nsel];
    const float C0sel = redc0[0][nsel] + redc0[1][nsel] + redc0[2][nsel] + redc0[3][nsel];

    // ---- K-half loop: 16 rows, 16 steps x 2 MFMA over cols [h*512, h*512+512) ----
    const int row0  = (int)blockIdx.x * 32 + t * 16;
    const int myrow = row0 + (lane & 15);
    const int rowc  = (myrow < nrows) ? myrow : (nrows - 1);
    const float* xrow = xg + (size_t)rowc * D_DIM + (lane >> 4) * 8 + h * 512;

    f32x4 acc1 = {0.f, 0.f, 0.f, 0.f};
    f32x4 acc2 = {0.f, 0.f, 0.f, 0.f};
    float s = 0.f, sq = 0.f;

    #pragma unroll 2
    for (int ks = 0; ks < 16; ++ks) {
        const float4 xa  = *(const float4*)(xrow + ks * 32);
        const float4 xb2 = *(const float4*)(xrow + ks * 32 + 4);
        s += ((xa.x + xa.y) + (xa.z + xa.w)) + ((xb2.x + xb2.y) + (xb2.z + xb2.w));
        sq = fmaf(xa.x, xa.x, sq);   sq = fmaf(xa.y, xa.y, sq);
        sq = fmaf(xa.z, xa.z, sq);   sq = fmaf(xa.w, xa.w, sq);
        sq = fmaf(xb2.x, xb2.x, sq); sq = fmaf(xb2.y, xb2.y, sq);
        sq = fmaf(xb2.z, xb2.z, sq); sq = fmaf(xb2.w, xb2.w, sq);

        const float xs0[8] = { xa.x, xa.y, xa.z, xa.w, xb2.x, xb2.y, xb2.z, xb2.w };
        bf16x8 xh, xl;
        #pragma unroll
        for (int e = 0; e < 8; ++e) {
            const unsigned hb = bf16_rne_bits(xs0[e]);
            xh[e] = (short)hb;
            xl[e] = (short)bf16_rne_bits(xs0[e] - bf16_bits_to_f(hb));
        }
        const bf16x8 bfr = *(const bf16x8*)&Bf[((h * 16 + ks) * 64 + lane) * 8];
        acc1 = __builtin_amdgcn_mfma_f32_16x16x32_bf16(xh, bfr, acc1, 0, 0, 0);
        acc2 = __builtin_amdgcn_mfma_f32_16x16x32_bf16(xl, bfr, acc2, 0, 0, 0);
    }

    // per-row s/sq partial over this K-half
    s  += __shfl_xor(s, 16, 64);  s  += __shfl_xor(s, 32, 64);
    sq += __shfl_xor(sq, 16, 64); sq += __shfl_xor(sq, 32, 64);
    if (lane < 16) { msbuf[t][h][lane][0] = s; msbuf[t][h][lane][1] = sq; }

    // z partials: combine hi/lo cols, write [row][n] (C/D layout per m89)
    const int grp = lane >> 4;
    #pragma unroll
    for (int r = 0; r < 4; ++r) {
        const float tt = acc1[r] + acc2[r];
        const float S = tt + __shfl_xor(tt, 8, 64);   // col n + col n+8 (Vl) partials
        if ((lane & 15) < 8) Sbuf[t][h][grp * 4 + r][lane & 7] = S;
    }
    __syncthreads();

    // ---- final phase: h==0 wave of each tile combines halves + epilogue ----
    if (h == 0) {
        const int r0a = lane >> 3;        // rows 0..7
        const int n   = lane & 7;
        unsigned rmaskw = 0u;

        #pragma unroll
        for (int half = 0; half < 2; ++half) {
            const int row = r0a + half * 8;
            const float S   = Sbuf[t][0][row][n] + Sbuf[t][1][row][n];
            const float sT  = msbuf[t][0][row][0] + msbuf[t][1][row][0];
            const float sqT = msbuf[t][0][row][1] + msbuf[t][1][row][1];
            const float mean = sT * (1.0f / 1024.0f);
            const float var  = sqT * (1.0f / 1024.0f) - mean * mean;
            const float rstd = 1.0f / sqrtf(var + 1e-5f);
            const float z = rstd * (S - mean * C1sel) + C0sel;

            int cnt = 0; float mind = 1e30f;
            #pragma unroll
            for (int k = 0; k < 8; ++k) {
                cnt += (z > tb.t[k]) ? 1 : 0;
                mind = fminf(mind, fabsf(z - tb.t[k]));
            }
            const int orow = row0 + row;
            const bool rok = (orow < nrows);
            if (rok) outg[(size_t)orow * NLEV + n] = (float)(cnt - 4);
            const bool fl = rok && (mind < 1.0e-3f);
            const unsigned long long bal = __ballot(fl);
            #pragma unroll
            for (int r = 0; r < 8; ++r)
                if ((bal >> (r * 8)) & 0xFFull) rmaskw |= 1u << (half * 8 + r);
        }

        // deferred fp64 repairs (~4% of rows; wave-uniform)
        while (rmaskw) {
            const int p = __builtin_ctz(rmaskw);
            rmaskw &= rmaskw - 1u;
            repair_row_reload(row0 + p, xg, gg, bg, Wg, outg, tbd, lane);
        }
    }
}

extern "C" void kernel_launch(void* const* d_in, const int* in_sizes, int n_in,
                              void* d_out, int out_size, void* d_ws, size_t ws_size,
                              hipStream_t stream) {
    (void)n_in; (void)out_size; (void)d_ws; (void)ws_size;  // workspace UNUSED
    const float* regrs = (const float*)d_in[0];
    const float* ln_w  = (const float*)d_in[1];
    const float* ln_b  = (const float*)d_in[2];
    const float* W     = (const float*)d_in[3];
    float* out = (float*)d_out;

    const int nrows = in_sizes[0] / D_DIM;      // 32768
    const int nblocks = (nrows + 31) / 32;      // 32 rows/block -> 1024 blocks = 4/CU

    TB tb; TBD tbd;
    for (int k = 0; k < 8; ++k) {
        const double y = ((double)k - 3.5) / 3.996;
        tbd.t[k] = atanh(y);           // fp64 z-space rounding boundaries
        tb.t[k]  = (float)tbd.t[k];
    }

    fsq_mfma<<<nblocks, 256, 0, stream>>>(regrs, ln_w, ln_b, W, out, nrows, tb, tbd);
}